// Round 13
// baseline (62.612 us; speedup 1.0000x reference)
//
#include <hip/hip_runtime.h>
#include <math.h>

#define BB 48
#define SS 1024
#define NCB (3 * BB)          // 144 combo-batches
#define NROW (BB * SS)
#define NBLK2 (NROW / 256)    // 192 epilogue blocks
#define NQUAD 256             // key-quads per combo-batch

typedef float f32x2 __attribute__((ext_vector_type(2)));
typedef int   i32x16 __attribute__((ext_vector_type(16)));
typedef int   i32x8  __attribute__((ext_vector_type(8)));

// ws layout (scalar path): part[8][NCB][SS] float4 | KV[NCB][NQUAD][24] |
// Qh[NCB][3][SS] | partial[NBLK2][18].
#define KV_FLOATS ((size_t)NCB * NQUAD * 24)
#define QH_FLOATS ((size_t)NCB * 3 * SS)

// Load one iteration's 24 K/V dwords through the scalar pipe.
// SINGLE asm block: issue + waitcnt together, so no compiler-inserted SGPR
// copy/spill can ever touch an in-flight s_load destination (R11/R12
// tripwire root cause). "=&s" early-clobber keeps dests off the address pair.
#define SLOADW(c16, c8, p)                                           \
    asm volatile("s_load_dwordx16 %0, %2, 0x0\n\t"                   \
                 "s_load_dwordx8  %1, %2, 0x40\n\t"                  \
                 "s_waitcnt lgkmcnt(0)"                              \
                 : "=&s"(c16), "=&s"(c8) : "s"(p))

// Kernel P: projections. KV interleaved [cb][quad][24] =
// k0[4],k1[4],k2[4],v0[4],v1[4],v2[4]; Q planar [cb][3][SS], pre-scaled by
// (1/sqrt(3))*log2(e) so attn's v_exp_f32(q.k) == exp(q.k/sqrt(3)).
__global__ __launch_bounds__(256) void mbfca_proj(
    const float* __restrict__ x,
    const float* __restrict__ WQ, const float* __restrict__ bQ,
    const float* __restrict__ WK, const float* __restrict__ bK,
    const float* __restrict__ WV, const float* __restrict__ bV,
    float* __restrict__ KV, float* __restrict__ Qh)
{
    const int cb = blockIdx.x;           // 0..143
    const int c  = cb / BB;
    const int b  = cb % BB;
    const int kband = c;
    const int vband = (c + 1) % 3;
    const int qband = (c + 2) % 3;
    const int t = threadIdx.x;           // key-quad 0..255

    const float* xk = x + (size_t)(kband * BB + b) * SS * 3;
    const float* xv = x + (size_t)(vband * BB + b) * SS * 3;
    const float* xq = x + (size_t)(qband * BB + b) * SS * 3;

    float wk[9], wv[9], wq[9], bk[3], bv[3], bq[3];
    const float qscale = 0.57735026918962576f * 1.4426950408889634f;
    #pragma unroll
    for (int i = 0; i < 9; ++i) {
        wk[i] = WK[kband * 9 + i];
        wv[i] = WV[vband * 9 + i];
        wq[i] = WQ[qband * 9 + i] * qscale;
    }
    #pragma unroll
    for (int i = 0; i < 3; ++i) {
        bk[i] = bK[kband * 3 + i];
        bv[i] = bV[vband * 3 + i];
        bq[i] = bQ[qband * 3 + i] * qscale;
    }

    // K/V: 4 keys of this quad -> 24 floats interleaved
    {
        const float4* k4 = reinterpret_cast<const float4*>(xk + 12 * t);
        const float4* v4 = reinterpret_cast<const float4*>(xv + 12 * t);
        float4 KA = k4[0], KB = k4[1], KC = k4[2];
        float4 VA = v4[0], VB = v4[1], VC = v4[2];
        float ka[12] = {KA.x, KA.y, KA.z, KA.w, KB.x, KB.y, KB.z, KB.w,
                        KC.x, KC.y, KC.z, KC.w};
        float va[12] = {VA.x, VA.y, VA.z, VA.w, VB.x, VB.y, VB.z, VB.w,
                        VC.x, VC.y, VC.z, VC.w};
        float out[24];
        #pragma unroll
        for (int j = 0; j < 4; ++j) {
            float a0 = ka[3 * j], a1 = ka[3 * j + 1], a2 = ka[3 * j + 2];
            out[0 + j]  = wk[0] * a0 + wk[1] * a1 + wk[2] * a2 + bk[0];
            out[4 + j]  = wk[3] * a0 + wk[4] * a1 + wk[5] * a2 + bk[1];
            out[8 + j]  = wk[6] * a0 + wk[7] * a1 + wk[8] * a2 + bk[2];
            float c0 = va[3 * j], c1 = va[3 * j + 1], c2 = va[3 * j + 2];
            out[12 + j] = wv[0] * c0 + wv[1] * c1 + wv[2] * c2 + bv[0];
            out[16 + j] = wv[3] * c0 + wv[4] * c1 + wv[5] * c2 + bv[1];
            out[20 + j] = wv[6] * c0 + wv[7] * c1 + wv[8] * c2 + bv[2];
        }
        float* dst = KV + ((size_t)cb * NQUAD + t) * 24;
        #pragma unroll
        for (int v = 0; v < 6; ++v)
            reinterpret_cast<float4*>(dst)[v] =
                make_float4(out[4 * v], out[4 * v + 1],
                            out[4 * v + 2], out[4 * v + 3]);
    }

    // Q: 4 queries of this quad -> planar
    {
        const float4* q4 = reinterpret_cast<const float4*>(xq + 12 * t);
        float4 QA = q4[0], QB = q4[1], QC = q4[2];
        float qa[12] = {QA.x, QA.y, QA.z, QA.w, QB.x, QB.y, QB.z, QB.w,
                        QC.x, QC.y, QC.z, QC.w};
        float o[3][4];
        #pragma unroll
        for (int j = 0; j < 4; ++j) {
            float a0 = qa[3 * j], a1 = qa[3 * j + 1], a2 = qa[3 * j + 2];
            o[0][j] = wq[0] * a0 + wq[1] * a1 + wq[2] * a2 + bq[0];
            o[1][j] = wq[3] * a0 + wq[4] * a1 + wq[5] * a2 + bq[1];
            o[2][j] = wq[6] * a0 + wq[7] * a1 + wq[8] * a2 + bq[2];
        }
        float* qdst = Qh + (size_t)cb * 3 * SS;
        #pragma unroll
        for (int p = 0; p < 3; ++p)
            reinterpret_cast<float4*>(qdst + (size_t)p * SS)[t] =
                make_float4(o[p][0], o[p][1], o[p][2], o[p][3]);
    }
}

// Kernel A (scalar path): K/V streamed through the SCALAR pipe (s_load ->
// SGPR broadcast operands). Serial load+wait per iteration (safe-by-
// construction); exposed K$-hit latency hidden by 4.5 waves/SIMD TLP.
template <int KSv>
__global__ __launch_bounds__(256) void mbfca_attn_s(
    const float* __restrict__ KV, const float* __restrict__ Qh,
    float* __restrict__ part)
{
    constexpr int NIT = (SS / KSv) / 4;  // key-quads per slice
    const int bid   = blockIdx.x;
    const int slice = bid % KSv;
    const int cb    = bid / KSv;
    const int tid   = threadIdx.x;

    // 4 queries/thread from planar pre-scaled Qh
    const float* qb = Qh + (size_t)cb * 3 * SS;
    float4 qv0 = reinterpret_cast<const float4*>(qb + 0 * SS)[tid];
    float4 qv1 = reinterpret_cast<const float4*>(qb + 1 * SS)[tid];
    float4 qv2 = reinterpret_cast<const float4*>(qb + 2 * SS)[tid];
    f32x2 qp0[4] = {{qv0.x,qv0.x},{qv0.y,qv0.y},{qv0.z,qv0.z},{qv0.w,qv0.w}};
    f32x2 qp1[4] = {{qv1.x,qv1.x},{qv1.y,qv1.y},{qv1.z,qv1.z},{qv1.w,qv1.w}};
    f32x2 qp2[4] = {{qv2.x,qv2.x},{qv2.y,qv2.y},{qv2.z,qv2.z},{qv2.w,qv2.w}};

    f32x2 lac[4], a0[4], a1[4], a2[4];
    #pragma unroll
    for (int j = 0; j < 4; ++j) {
        lac[j] = (f32x2){0.f, 0.f};
        a0[j]  = (f32x2){0.f, 0.f};
        a1[j]  = (f32x2){0.f, 0.f};
        a2[j]  = (f32x2){0.f, 0.f};
    }

    const float* kv = KV + ((size_t)cb * NQUAD + slice * NIT) * 24;

    for (int t = 0; t < NIT; ++t) {
        i32x16 c16;
        i32x8  c8;
        SLOADW(c16, c8, kv + (size_t)t * 24);

        f32x2 k0l = {__int_as_float(c16[0]),  __int_as_float(c16[1])};
        f32x2 k0h = {__int_as_float(c16[2]),  __int_as_float(c16[3])};
        f32x2 k1l = {__int_as_float(c16[4]),  __int_as_float(c16[5])};
        f32x2 k1h = {__int_as_float(c16[6]),  __int_as_float(c16[7])};
        f32x2 k2l = {__int_as_float(c16[8]),  __int_as_float(c16[9])};
        f32x2 k2h = {__int_as_float(c16[10]), __int_as_float(c16[11])};
        f32x2 v0l = {__int_as_float(c16[12]), __int_as_float(c16[13])};
        f32x2 v0h = {__int_as_float(c16[14]), __int_as_float(c16[15])};
        f32x2 v1l = {__int_as_float(c8[0]),   __int_as_float(c8[1])};
        f32x2 v1h = {__int_as_float(c8[2]),   __int_as_float(c8[3])};
        f32x2 v2l = {__int_as_float(c8[4]),   __int_as_float(c8[5])};
        f32x2 v2h = {__int_as_float(c8[6]),   __int_as_float(c8[7])};

        f32x2 sl[4], sh[4];
        #pragma unroll
        for (int j = 0; j < 4; ++j) {
            sl[j] = qp0[j] * k0l + qp1[j] * k1l + qp2[j] * k2l;
            sh[j] = qp0[j] * k0h + qp1[j] * k1h + qp2[j] * k2h;
        }
        f32x2 pl[4], ph[4];
        #pragma unroll
        for (int j = 0; j < 4; ++j) {
            pl[j].x = __builtin_amdgcn_exp2f(sl[j].x);
            pl[j].y = __builtin_amdgcn_exp2f(sl[j].y);
            ph[j].x = __builtin_amdgcn_exp2f(sh[j].x);
            ph[j].y = __builtin_amdgcn_exp2f(sh[j].y);
        }
        #pragma unroll
        for (int j = 0; j < 4; ++j) {
            lac[j] += pl[j] + ph[j];
            a0[j]  += pl[j] * v0l + ph[j] * v0h;
            a1[j]  += pl[j] * v1l + ph[j] * v1h;
            a2[j]  += pl[j] * v2l + ph[j] * v2h;
        }
    }

    float4* dst = reinterpret_cast<float4*>(part) +
                  ((size_t)(slice * NCB + cb) * SS + 4 * tid);
    #pragma unroll
    for (int j = 0; j < 4; ++j)
        dst[j] = make_float4(a0[j].x + a0[j].y,
                             a1[j].x + a1[j].y,
                             a2[j].x + a2[j].y,
                             lac[j].x + lac[j].y);
}

// Fallback kernel (small ws): R10's LDS-staged attention.
template <int KSv>
__global__ __launch_bounds__(256) void mbfca_attn_lds(
    const float* __restrict__ x,
    const float* __restrict__ WQ, const float* __restrict__ bQ,
    const float* __restrict__ WK, const float* __restrict__ bK,
    const float* __restrict__ WV, const float* __restrict__ bV,
    float* __restrict__ part)
{
    constexpr int SSK = SS / KSv;
    const int bid   = blockIdx.x;
    const int slice = bid % KSv;
    const int cb    = bid / KSv;
    const int c     = cb / BB;
    const int b     = cb % BB;
    const int kband = c, vband = (c + 1) % 3, qband = (c + 2) % 3;

    __shared__ __align__(16) float Ksm[3][SSK];
    __shared__ __align__(16) float Vsm[3][SSK];
    const int tid = threadIdx.x;

    const float* xk = x + (size_t)(kband * BB + b) * SS * 3;
    const float* xv = x + (size_t)(vband * BB + b) * SS * 3;
    const float* xq = x + (size_t)(qband * BB + b) * SS * 3;

    {
        float wk[9], wv[9], bk[3], bv[3];
        #pragma unroll
        for (int i = 0; i < 9; ++i) { wk[i] = WK[kband * 9 + i]; wv[i] = WV[vband * 9 + i]; }
        #pragma unroll
        for (int i = 0; i < 3; ++i) { bk[i] = bK[kband * 3 + i]; bv[i] = bV[vband * 3 + i]; }
        for (int t = tid; t < SSK; t += 256) {
            const int tk = slice * SSK + t;
            float a0 = xk[tk * 3 + 0], a1 = xk[tk * 3 + 1], a2 = xk[tk * 3 + 2];
            Ksm[0][t] = wk[0] * a0 + wk[1] * a1 + wk[2] * a2 + bk[0];
            Ksm[1][t] = wk[3] * a0 + wk[4] * a1 + wk[5] * a2 + bk[1];
            Ksm[2][t] = wk[6] * a0 + wk[7] * a1 + wk[8] * a2 + bk[2];
            float c0 = xv[tk * 3 + 0], c1 = xv[tk * 3 + 1], c2 = xv[tk * 3 + 2];
            Vsm[0][t] = wv[0] * c0 + wv[1] * c1 + wv[2] * c2 + bv[0];
            Vsm[1][t] = wv[3] * c0 + wv[4] * c1 + wv[5] * c2 + bv[1];
            Vsm[2][t] = wv[6] * c0 + wv[7] * c1 + wv[8] * c2 + bv[2];
        }
    }
    __syncthreads();

    f32x2 qp0[4], qp1[4], qp2[4];
    {
        float wq[9], bq[3];
        const float qscale = 0.57735026918962576f * 1.4426950408889634f;
        #pragma unroll
        for (int i = 0; i < 9; ++i) wq[i] = WQ[qband * 9 + i] * qscale;
        #pragma unroll
        for (int i = 0; i < 3; ++i) bq[i] = bQ[qband * 3 + i] * qscale;
        const float4* xq4 = reinterpret_cast<const float4*>(xq + 12 * tid);
        float4 A = xq4[0], B4 = xq4[1], C4 = xq4[2];
        float a[12] = {A.x, A.y, A.z, A.w, B4.x, B4.y, B4.z, B4.w,
                       C4.x, C4.y, C4.z, C4.w};
        #pragma unroll
        for (int j = 0; j < 4; ++j) {
            float a0 = a[3 * j], a1 = a[3 * j + 1], a2 = a[3 * j + 2];
            float t0 = wq[0] * a0 + wq[1] * a1 + wq[2] * a2 + bq[0];
            float t1 = wq[3] * a0 + wq[4] * a1 + wq[5] * a2 + bq[1];
            float t2 = wq[6] * a0 + wq[7] * a1 + wq[8] * a2 + bq[2];
            qp0[j] = (f32x2){t0, t0};
            qp1[j] = (f32x2){t1, t1};
            qp2[j] = (f32x2){t2, t2};
        }
    }

    f32x2 lac[4], a0[4], a1[4], a2[4];
    #pragma unroll
    for (int j = 0; j < 4; ++j) {
        lac[j] = (f32x2){0.f, 0.f};
        a0[j]  = (f32x2){0.f, 0.f};
        a1[j]  = (f32x2){0.f, 0.f};
        a2[j]  = (f32x2){0.f, 0.f};
    }

    const float4* K0 = reinterpret_cast<const float4*>(&Ksm[0][0]);
    const float4* K1 = reinterpret_cast<const float4*>(&Ksm[1][0]);
    const float4* K2 = reinterpret_cast<const float4*>(&Ksm[2][0]);
    const float4* V0 = reinterpret_cast<const float4*>(&Vsm[0][0]);
    const float4* V1 = reinterpret_cast<const float4*>(&Vsm[1][0]);
    const float4* V2 = reinterpret_cast<const float4*>(&Vsm[2][0]);

    for (int t4 = 0; t4 < SSK / 4; ++t4) {
        float4 k0 = K0[t4], k1 = K1[t4], k2 = K2[t4];
        float4 v0 = V0[t4], v1 = V1[t4], v2 = V2[t4];
        f32x2 k0l = {k0.x, k0.y}, k0h = {k0.z, k0.w};
        f32x2 k1l = {k1.x, k1.y}, k1h = {k1.z, k1.w};
        f32x2 k2l = {k2.x, k2.y}, k2h = {k2.z, k2.w};
        f32x2 v0l = {v0.x, v0.y}, v0h = {v0.z, v0.w};
        f32x2 v1l = {v1.x, v1.y}, v1h = {v1.z, v1.w};
        f32x2 v2l = {v2.x, v2.y}, v2h = {v2.z, v2.w};
        #pragma unroll
        for (int j = 0; j < 4; ++j) {
            f32x2 sl = qp0[j] * k0l + qp1[j] * k1l + qp2[j] * k2l;
            f32x2 sh = qp0[j] * k0h + qp1[j] * k1h + qp2[j] * k2h;
            f32x2 pl, ph;
            pl.x = __builtin_amdgcn_exp2f(sl.x);
            pl.y = __builtin_amdgcn_exp2f(sl.y);
            ph.x = __builtin_amdgcn_exp2f(sh.x);
            ph.y = __builtin_amdgcn_exp2f(sh.y);
            lac[j] += pl + ph;
            a0[j]  += pl * v0l + ph * v0h;
            a1[j]  += pl * v1l + ph * v1h;
            a2[j]  += pl * v2l + ph * v2h;
        }
    }

    float4* dst = reinterpret_cast<float4*>(part) +
                  ((size_t)(slice * NCB + cb) * SS + 4 * tid);
    #pragma unroll
    for (int j = 0; j < 4; ++j)
        dst[j] = make_float4(a0[j].x + a0[j].y,
                             a1[j].x + a1[j].y,
                             a2[j].x + a2[j].y,
                             lac[j].x + lac[j].y);
}

// Kernel 2: reduce slices -> o (in-place to part slice 0), BN partials.
template <int KSv>
__global__ __launch_bounds__(256) void mbfca_stats(
    float* __restrict__ part, float* __restrict__ partial)
{
    const int r = blockIdx.x * 256 + threadIdx.x;
    const int b = r >> 10, s = r & 1023;
    __shared__ float red[4][18];

    float sums[18];
    #pragma unroll
    for (int k = 0; k < 18; ++k) sums[k] = 0.f;

    float4* p4 = reinterpret_cast<float4*>(part);
    #pragma unroll
    for (int c = 0; c < 3; ++c) {
        const int cb = c * BB + b;
        float4 t = make_float4(0.f, 0.f, 0.f, 0.f);
        #pragma unroll
        for (int sl = 0; sl < KSv; ++sl) {
            float4 u = p4[(size_t)(sl * NCB + cb) * SS + s];
            t.x += u.x; t.y += u.y; t.z += u.z; t.w += u.w;
        }
        float inv = 1.0f / t.w;
        float o0 = t.x * inv, o1 = t.y * inv, o2 = t.z * inv;
        p4[(size_t)cb * SS + s] = make_float4(o0, o1, o2, 0.f);
        sums[3 * c + 0] = o0;          sums[3 * c + 1] = o1;          sums[3 * c + 2] = o2;
        sums[9 + 3 * c + 0] = o0 * o0; sums[9 + 3 * c + 1] = o1 * o1; sums[9 + 3 * c + 2] = o2 * o2;
    }

    #pragma unroll
    for (int off = 32; off >= 1; off >>= 1)
        #pragma unroll
        for (int k = 0; k < 18; ++k)
            sums[k] += __shfl_xor(sums[k], off, 64);

    const int tid = threadIdx.x;
    if ((tid & 63) == 0) {
        #pragma unroll
        for (int k = 0; k < 18; ++k) red[tid >> 6][k] = sums[k];
    }
    __syncthreads();
    if (tid < 18)
        partial[blockIdx.x * 18 + tid] =
            red[0][tid] + red[1][tid] + red[2][tid] + red[3][tid];
}

// Kernel 3: reduce per-block partials -> BN scale/shift; compact o -> y.
__global__ __launch_bounds__(256) void mbfca_bnfc(
    const float* __restrict__ part, const float* __restrict__ partial,
    const float* __restrict__ gamma, const float* __restrict__ beta,
    const float* __restrict__ fcw, const float* __restrict__ fcb,
    float* __restrict__ out)
{
    __shared__ float red[4][18];
    __shared__ float accs[18];
    const int tid = threadIdx.x;

    float sums[18];
    #pragma unroll
    for (int k = 0; k < 18; ++k) sums[k] = 0.f;
    if (tid < NBLK2) {
        #pragma unroll
        for (int k = 0; k < 18; ++k) sums[k] = partial[tid * 18 + k];
    }
    #pragma unroll
    for (int off = 32; off >= 1; off >>= 1)
        #pragma unroll
        for (int k = 0; k < 18; ++k)
            sums[k] += __shfl_xor(sums[k], off, 64);
    if ((tid & 63) == 0) {
        #pragma unroll
        for (int k = 0; k < 18; ++k) red[tid >> 6][k] = sums[k];
    }
    __syncthreads();
    if (tid < 18)
        accs[tid] = red[0][tid] + red[1][tid] + red[2][tid] + red[3][tid];
    __syncthreads();

    const int r = blockIdx.x * 256 + tid;
    const int b = r >> 10, s = r & 1023;
    const float invN = 1.0f / (float)NROW;

    float sc[9], sh[9];
    #pragma unroll
    for (int ch = 0; ch < 9; ++ch) {
        float mean = accs[ch] * invN;
        float var  = accs[9 + ch] * invN - mean * mean;
        float sfac = gamma[ch] * rsqrtf(var + 1e-5f);
        sc[ch] = sfac;
        sh[ch] = beta[ch] - mean * sfac;
    }

    const float4* p4 = reinterpret_cast<const float4*>(part);
    float y0 = fcb[0], y1 = fcb[1], y2 = fcb[2];
    #pragma unroll
    for (int c = 0; c < 3; ++c) {
        const int cb = c * BB + b;
        float4 t = p4[(size_t)cb * SS + s];
        float o[3] = {t.x, t.y, t.z};
        #pragma unroll
        for (int e = 0; e < 3; ++e) {
            float n = o[e] * sc[3 * c + e] + sh[3 * c + e];
            y0 += n * fcw[3 * c + e];
            y1 += n * fcw[9 + 3 * c + e];
            y2 += n * fcw[18 + 3 * c + e];
        }
    }
    out[r * 3 + 0] = y0;
    out[r * 3 + 1] = y1;
    out[r * 3 + 2] = y2;
}

extern "C" void kernel_launch(void* const* d_in, const int* in_sizes, int n_in,
                              void* d_out, int out_size, void* d_ws, size_t ws_size,
                              hipStream_t stream)
{
    const float* x     = (const float*)d_in[0];
    const float* WQ    = (const float*)d_in[1];
    const float* bQv   = (const float*)d_in[2];
    const float* WK    = (const float*)d_in[3];
    const float* bKv   = (const float*)d_in[4];
    const float* WV    = (const float*)d_in[5];
    const float* bVv   = (const float*)d_in[6];
    const float* gamma = (const float*)d_in[7];
    const float* beta  = (const float*)d_in[8];
    const float* fcw   = (const float*)d_in[9];
    const float* fcb   = (const float*)d_in[10];

    float* ws = (float*)d_ws;

    constexpr int KS = 8;
    const size_t part_f = (size_t)KS * NCB * SS * 4;
    const size_t need_s = (part_f + KV_FLOATS + QH_FLOATS
                           + (size_t)NBLK2 * 18) * sizeof(float);

    if (ws_size >= need_s) {
        float* part    = ws;
        float* KV      = part + part_f;
        float* Qh      = KV + KV_FLOATS;
        float* partial = Qh + QH_FLOATS;
        mbfca_proj<<<dim3(NCB), dim3(256), 0, stream>>>(
            x, WQ, bQv, WK, bKv, WV, bVv, KV, Qh);
        mbfca_attn_s<KS><<<dim3(NCB * KS), dim3(256), 0, stream>>>(
            KV, Qh, part);
        mbfca_stats<KS><<<dim3(NBLK2), dim3(256), 0, stream>>>(part, partial);
        mbfca_bnfc<<<dim3(NBLK2), dim3(256), 0, stream>>>(
            part, partial, gamma, beta, fcw, fcb, (float*)d_out);
    } else {
        float* part    = ws;
        float* partial = part + (size_t)4 * NCB * SS * 4;
        mbfca_attn_lds<4><<<dim3(NCB * 4), dim3(256), 0, stream>>>(
            x, WQ, bQv, WK, bKv, WV, bVv, part);
        mbfca_stats<4><<<dim3(NBLK2), dim3(256), 0, stream>>>(part, partial);
        mbfca_bnfc<<<dim3(NBLK2), dim3(256), 0, stream>>>(
            part, partial, gamma, beta, fcw, fcb, (float*)d_out);
    }
}

// Round 14
// 52.982 us; speedup vs baseline: 1.1818x; 1.1818x over previous
//
#include <hip/hip_runtime.h>
#include <math.h>

#define BB 48
#define SS 1024
#define NCB (3 * BB)          // 144 combo-batches
#define NROW (BB * SS)
#define NBLK2 (NROW / 256)    // 192 epilogue blocks

typedef float f32x2 __attribute__((ext_vector_type(2)));

// ws layout: part[KS][NCB][SS] float4 (A0,A1,A2,l) | partial[NBLK2][18].
// stats overwrites part slice 0 with o in-place (race-free, 1 thread/slot).
//
// R14 = R10 restored verbatim (best measured config: 52.6 us).
// Session conclusion: attn wall ~41 us is the VALU+trans issue floor plus
// non-overlapping memory-pipe issue; occupancy (10->35%), LDS<->L1 swap,
// q=8 traffic halving, prefetch/batching, and scalar-pipe streaming all
// failed to move it (R5-R13).

template <int KSv>
__global__ __launch_bounds__(256) void mbfca_attn(
    const float* __restrict__ x,
    const float* __restrict__ WQ, const float* __restrict__ bQ,
    const float* __restrict__ WK, const float* __restrict__ bK,
    const float* __restrict__ WV, const float* __restrict__ bV,
    float* __restrict__ part)
{
    constexpr int SSK = SS / KSv;        // keys per slice
    constexpr int NIT = SSK / 4;         // inner iterations
    const int bid   = blockIdx.x;
    const int slice = bid % KSv;
    const int cb    = bid / KSv;         // 0..143
    const int c     = cb / BB;
    const int b     = cb % BB;
    const int kband = c;
    const int vband = (c + 1) % 3;
    const int qband = (c + 2) % 3;

    __shared__ __align__(16) float Ksm[3][SSK];
    __shared__ __align__(16) float Vsm[3][SSK];

    const int tid = threadIdx.x;

    const float* xk = x + (size_t)(kband * BB + b) * SS * 3;
    const float* xv = x + (size_t)(vband * BB + b) * SS * 3;
    const float* xq = x + (size_t)(qband * BB + b) * SS * 3;

    // stage this slice's projected K,V
    {
        float wk[9], wv[9], bk[3], bv[3];
        #pragma unroll
        for (int i = 0; i < 9; ++i) { wk[i] = WK[kband * 9 + i]; wv[i] = WV[vband * 9 + i]; }
        #pragma unroll
        for (int i = 0; i < 3; ++i) { bk[i] = bK[kband * 3 + i]; bv[i] = bV[vband * 3 + i]; }
        for (int t = tid; t < SSK; t += 256) {
            const int tk = slice * SSK + t;
            float a0 = xk[tk * 3 + 0], a1 = xk[tk * 3 + 1], a2 = xk[tk * 3 + 2];
            Ksm[0][t] = wk[0] * a0 + wk[1] * a1 + wk[2] * a2 + bk[0];
            Ksm[1][t] = wk[3] * a0 + wk[4] * a1 + wk[5] * a2 + bk[1];
            Ksm[2][t] = wk[6] * a0 + wk[7] * a1 + wk[8] * a2 + bk[2];
            float c0 = xv[tk * 3 + 0], c1 = xv[tk * 3 + 1], c2 = xv[tk * 3 + 2];
            Vsm[0][t] = wv[0] * c0 + wv[1] * c1 + wv[2] * c2 + bv[0];
            Vsm[1][t] = wv[3] * c0 + wv[4] * c1 + wv[5] * c2 + bv[1];
            Vsm[2][t] = wv[6] * c0 + wv[7] * c1 + wv[8] * c2 + bv[2];
        }
    }
    __syncthreads();

    // 4 queries/thread: s = 4*tid + j, pre-scaled by (1/sqrt(3))*log2(e)
    f32x2 qp0[4], qp1[4], qp2[4];
    {
        float wq[9], bq[3];
        const float qscale = 0.57735026918962576f * 1.4426950408889634f;
        #pragma unroll
        for (int i = 0; i < 9; ++i) wq[i] = WQ[qband * 9 + i] * qscale;
        #pragma unroll
        for (int i = 0; i < 3; ++i) bq[i] = bQ[qband * 3 + i] * qscale;
        const float4* xq4 = reinterpret_cast<const float4*>(xq + 12 * tid);
        float4 A = xq4[0], B4 = xq4[1], C4 = xq4[2];
        float a[12] = {A.x, A.y, A.z, A.w, B4.x, B4.y, B4.z, B4.w,
                       C4.x, C4.y, C4.z, C4.w};
        #pragma unroll
        for (int j = 0; j < 4; ++j) {
            float a0 = a[3 * j], a1 = a[3 * j + 1], a2 = a[3 * j + 2];
            float t0 = wq[0] * a0 + wq[1] * a1 + wq[2] * a2 + bq[0];
            float t1 = wq[3] * a0 + wq[4] * a1 + wq[5] * a2 + bq[1];
            float t2 = wq[6] * a0 + wq[7] * a1 + wq[8] * a2 + bq[2];
            qp0[j] = (f32x2){t0, t0};
            qp1[j] = (f32x2){t1, t1};
            qp2[j] = (f32x2){t2, t2};
        }
    }

    f32x2 lac[4], a0[4], a1[4], a2[4];
    #pragma unroll
    for (int j = 0; j < 4; ++j) {
        lac[j] = (f32x2){0.f, 0.f};
        a0[j]  = (f32x2){0.f, 0.f};
        a1[j]  = (f32x2){0.f, 0.f};
        a2[j]  = (f32x2){0.f, 0.f};
    }

    const float4* K0 = reinterpret_cast<const float4*>(&Ksm[0][0]);
    const float4* K1 = reinterpret_cast<const float4*>(&Ksm[1][0]);
    const float4* K2 = reinterpret_cast<const float4*>(&Ksm[2][0]);
    const float4* V0 = reinterpret_cast<const float4*>(&Vsm[0][0]);
    const float4* V1 = reinterpret_cast<const float4*>(&Vsm[1][0]);
    const float4* V2 = reinterpret_cast<const float4*>(&Vsm[2][0]);

    // batched body: scores -> exps -> accumulates (exp-latency distance)
    auto body = [&](float4 k0, float4 k1, float4 k2,
                    float4 v0, float4 v1, float4 v2) {
        f32x2 k0l = {k0.x, k0.y}, k0h = {k0.z, k0.w};
        f32x2 k1l = {k1.x, k1.y}, k1h = {k1.z, k1.w};
        f32x2 k2l = {k2.x, k2.y}, k2h = {k2.z, k2.w};
        f32x2 v0l = {v0.x, v0.y}, v0h = {v0.z, v0.w};
        f32x2 v1l = {v1.x, v1.y}, v1h = {v1.z, v1.w};
        f32x2 v2l = {v2.x, v2.y}, v2h = {v2.z, v2.w};
        f32x2 sl[4], sh[4];
        #pragma unroll
        for (int j = 0; j < 4; ++j) {
            sl[j] = qp0[j] * k0l + qp1[j] * k1l + qp2[j] * k2l;
            sh[j] = qp0[j] * k0h + qp1[j] * k1h + qp2[j] * k2h;
        }
        f32x2 pl[4], ph[4];
        #pragma unroll
        for (int j = 0; j < 4; ++j) {
            pl[j].x = __builtin_amdgcn_exp2f(sl[j].x);
            pl[j].y = __builtin_amdgcn_exp2f(sl[j].y);
            ph[j].x = __builtin_amdgcn_exp2f(sh[j].x);
            ph[j].y = __builtin_amdgcn_exp2f(sh[j].y);
        }
        #pragma unroll
        for (int j = 0; j < 4; ++j) {
            lac[j] += pl[j] + ph[j];
            a0[j]  += pl[j] * v0l + ph[j] * v0h;
            a1[j]  += pl[j] * v1l + ph[j] * v1h;
            a2[j]  += pl[j] * v2l + ph[j] * v2h;
        }
    };

    // register double-buffer: prefetch t4+1 while computing t4
    float4 k0 = K0[0], k1 = K1[0], k2 = K2[0];
    float4 v0 = V0[0], v1 = V1[0], v2 = V2[0];
    #pragma unroll 2
    for (int t4 = 0; t4 < NIT - 1; ++t4) {
        float4 nk0 = K0[t4 + 1], nk1 = K1[t4 + 1], nk2 = K2[t4 + 1];
        float4 nv0 = V0[t4 + 1], nv1 = V1[t4 + 1], nv2 = V2[t4 + 1];
        body(k0, k1, k2, v0, v1, v2);
        k0 = nk0; k1 = nk1; k2 = nk2;
        v0 = nv0; v1 = nv1; v2 = nv2;
    }
    body(k0, k1, k2, v0, v1, v2);

    float4* dst = reinterpret_cast<float4*>(part) +
                  ((size_t)(slice * NCB + cb) * SS + 4 * tid);
    #pragma unroll
    for (int j = 0; j < 4; ++j)
        dst[j] = make_float4(a0[j].x + a0[j].y,
                             a1[j].x + a1[j].y,
                             a2[j].x + a2[j].y,
                             lac[j].x + lac[j].y);
}

// Kernel 2: reduce slices -> o (in-place to part slice 0), BN partials.
template <int KSv>
__global__ __launch_bounds__(256) void mbfca_stats(
    float* __restrict__ part, float* __restrict__ partial)
{
    const int r = blockIdx.x * 256 + threadIdx.x;   // row 0..49151
    const int b = r >> 10, s = r & 1023;
    __shared__ float red[4][18];

    float sums[18];
    #pragma unroll
    for (int k = 0; k < 18; ++k) sums[k] = 0.f;

    float4* p4 = reinterpret_cast<float4*>(part);
    #pragma unroll
    for (int c = 0; c < 3; ++c) {
        const int cb = c * BB + b;
        float4 t = make_float4(0.f, 0.f, 0.f, 0.f);
        #pragma unroll
        for (int sl = 0; sl < KSv; ++sl) {
            float4 u = p4[(size_t)(sl * NCB + cb) * SS + s];
            t.x += u.x; t.y += u.y; t.z += u.z; t.w += u.w;
        }
        float inv = 1.0f / t.w;
        float o0 = t.x * inv, o1 = t.y * inv, o2 = t.z * inv;
        p4[(size_t)cb * SS + s] = make_float4(o0, o1, o2, 0.f);  // in-place o
        sums[3 * c + 0] = o0;          sums[3 * c + 1] = o1;          sums[3 * c + 2] = o2;
        sums[9 + 3 * c + 0] = o0 * o0; sums[9 + 3 * c + 1] = o1 * o1; sums[9 + 3 * c + 2] = o2 * o2;
    }

    #pragma unroll
    for (int off = 32; off >= 1; off >>= 1)
        #pragma unroll
        for (int k = 0; k < 18; ++k)
            sums[k] += __shfl_xor(sums[k], off, 64);

    const int tid = threadIdx.x;
    if ((tid & 63) == 0) {
        #pragma unroll
        for (int k = 0; k < 18; ++k) red[tid >> 6][k] = sums[k];
    }
    __syncthreads();
    if (tid < 18)
        partial[blockIdx.x * 18 + tid] =
            red[0][tid] + red[1][tid] + red[2][tid] + red[3][tid];
}

// Kernel 3: reduce per-block partials -> BN scale/shift; compact o -> y.
__global__ __launch_bounds__(256) void mbfca_bnfc(
    const float* __restrict__ part, const float* __restrict__ partial,
    const float* __restrict__ gamma, const float* __restrict__ beta,
    const float* __restrict__ fcw, const float* __restrict__ fcb,
    float* __restrict__ out)
{
    __shared__ float red[4][18];
    __shared__ float accs[18];
    const int tid = threadIdx.x;

    float sums[18];
    #pragma unroll
    for (int k = 0; k < 18; ++k) sums[k] = 0.f;
    if (tid < NBLK2) {
        #pragma unroll
        for (int k = 0; k < 18; ++k) sums[k] = partial[tid * 18 + k];
    }
    #pragma unroll
    for (int off = 32; off >= 1; off >>= 1)
        #pragma unroll
        for (int k = 0; k < 18; ++k)
            sums[k] += __shfl_xor(sums[k], off, 64);
    if ((tid & 63) == 0) {
        #pragma unroll
        for (int k = 0; k < 18; ++k) red[tid >> 6][k] = sums[k];
    }
    __syncthreads();
    if (tid < 18)
        accs[tid] = red[0][tid] + red[1][tid] + red[2][tid] + red[3][tid];
    __syncthreads();

    const int r = blockIdx.x * 256 + tid;
    const int b = r >> 10, s = r & 1023;
    const float invN = 1.0f / (float)NROW;

    float sc[9], sh[9];
    #pragma unroll
    for (int ch = 0; ch < 9; ++ch) {
        float mean = accs[ch] * invN;
        float var  = accs[9 + ch] * invN - mean * mean;  // biased variance
        float sfac = gamma[ch] * rsqrtf(var + 1e-5f);
        sc[ch] = sfac;
        sh[ch] = beta[ch] - mean * sfac;
    }

    const float4* p4 = reinterpret_cast<const float4*>(part);
    float y0 = fcb[0], y1 = fcb[1], y2 = fcb[2];
    #pragma unroll
    for (int c = 0; c < 3; ++c) {
        const int cb = c * BB + b;
        float4 t = p4[(size_t)cb * SS + s];
        float o[3] = {t.x, t.y, t.z};
        #pragma unroll
        for (int e = 0; e < 3; ++e) {
            float n = o[e] * sc[3 * c + e] + sh[3 * c + e];
            y0 += n * fcw[3 * c + e];
            y1 += n * fcw[9 + 3 * c + e];
            y2 += n * fcw[18 + 3 * c + e];
        }
    }
    out[r * 3 + 0] = y0;
    out[r * 3 + 1] = y1;
    out[r * 3 + 2] = y2;
}

template <int KSv>
static void run_pipeline(const float* x, const float* WQ, const float* bQ,
                         const float* WK, const float* bK,
                         const float* WV, const float* bV,
                         const float* gamma, const float* beta,
                         const float* fcw, const float* fcb,
                         float* ws, float* out, hipStream_t stream)
{
    float* part    = ws;
    float* partial = part + (size_t)KSv * NCB * SS * 4;

    mbfca_attn<KSv><<<dim3(NCB * KSv), dim3(256), 0, stream>>>(
        x, WQ, bQ, WK, bK, WV, bV, part);
    mbfca_stats<KSv><<<dim3(NBLK2), dim3(256), 0, stream>>>(part, partial);
    mbfca_bnfc<<<dim3(NBLK2), dim3(256), 0, stream>>>(
        part, partial, gamma, beta, fcw, fcb, out);
}

extern "C" void kernel_launch(void* const* d_in, const int* in_sizes, int n_in,
                              void* d_out, int out_size, void* d_ws, size_t ws_size,
                              hipStream_t stream)
{
    const float* x     = (const float*)d_in[0];
    const float* WQ    = (const float*)d_in[1];
    const float* bQv   = (const float*)d_in[2];
    const float* WK    = (const float*)d_in[3];
    const float* bKv   = (const float*)d_in[4];
    const float* WV    = (const float*)d_in[5];
    const float* bVv   = (const float*)d_in[6];
    const float* gamma = (const float*)d_in[7];
    const float* beta  = (const float*)d_in[8];
    const float* fcw   = (const float*)d_in[9];
    const float* fcb   = (const float*)d_in[10];

    float* ws = (float*)d_ws;

    const size_t tail   = (size_t)NBLK2 * 18 * sizeof(float);
    const size_t need16 = (size_t)16 * NCB * SS * 4 * sizeof(float) + tail;
    const size_t need8  = (size_t)8  * NCB * SS * 4 * sizeof(float) + tail;

    if (ws_size >= need16) {
        run_pipeline<16>(x, WQ, bQv, WK, bKv, WV, bVv, gamma, beta, fcw, fcb,
                         ws, (float*)d_out, stream);
    } else if (ws_size >= need8) {
        run_pipeline<8>(x, WQ, bQv, WK, bKv, WV, bVv, gamma, beta, fcw, fcb,
                        ws, (float*)d_out, stream);
    } else {
        run_pipeline<4>(x, WQ, bQv, WK, bKv, WV, bVv, gamma, beta, fcw, fcb,
                        ws, (float*)d_out, stream);
    }
}